// Round 1
// baseline (1412.939 us; speedup 1.0000x reference)
//
#include <hip/hip_runtime.h>
#include <hip/hip_bf16.h>
#include <math.h>

#define B_ 64
#define N_ 1024
#define E_ 16

__device__ __forceinline__ float sigmoidf_(float x) {
  return 1.0f / (1.0f + __expf(-x));
}

// ---------- A = softmax(relu(emb @ emb^T), axis=1) ----------
__global__ __launch_bounds__(256) void compute_A_kernel(const float* __restrict__ emb,
                                                        float* __restrict__ A) {
  __shared__ float embn[E_];
  __shared__ float red[256];
  const int n = blockIdx.x;
  const int t = threadIdx.x;
  if (t < E_) embn[t] = emb[n * E_ + t];
  __syncthreads();
  float s[4];
#pragma unroll
  for (int j = 0; j < 4; ++j) {
    const int m = j * 256 + t;
    const float* em = emb + m * E_;
    float acc = 0.f;
#pragma unroll
    for (int d = 0; d < E_; ++d) acc = fmaf(embn[d], em[d], acc);
    s[j] = fmaxf(acc, 0.f);
  }
  float mx = fmaxf(fmaxf(s[0], s[1]), fmaxf(s[2], s[3]));
  red[t] = mx;
  __syncthreads();
  for (int off = 128; off > 0; off >>= 1) {
    if (t < off) red[t] = fmaxf(red[t], red[t + off]);
    __syncthreads();
  }
  mx = red[0];
  __syncthreads();
  float e[4], lsum = 0.f;
#pragma unroll
  for (int j = 0; j < 4; ++j) { e[j] = __expf(s[j] - mx); lsum += e[j]; }
  red[t] = lsum;
  __syncthreads();
  for (int off = 128; off > 0; off >>= 1) {
    if (t < off) red[t] += red[t + off];
    __syncthreads();
  }
  const float inv = 1.0f / red[0];
#pragma unroll
  for (int j = 0; j < 4; ++j) A[n * N_ + j * 256 + t] = e[j] * inv;
}

// ---------- T0[n][b][c] = c<64 ? xa[b,n,c] : xb[b,n,c-64] ----------
__global__ __launch_bounds__(256) void build_T0_kernel(const float* __restrict__ xa,
                                                       const float* __restrict__ xb,
                                                       float* __restrict__ T0) {
  const int idx = blockIdx.x * 256 + threadIdx.x;
  const int c = idx & 127;
  const int b = (idx >> 7) & 63;
  const int n = idx >> 13;
  const int src = (b << 16) + (n << 6);
  T0[idx] = (c < 64) ? xa[src + c] : xb[src + c - 64];
}

// ---------- C = alpha*A@B (+ beta*Cin) ; 128x128 tile, 8x8 microtile ----------
template <int HAS_C>
__global__ __launch_bounds__(256) void sgemm_kernel(const float* __restrict__ A,
                                                    const float* __restrict__ Bm,
                                                    const float* __restrict__ Cin,
                                                    float* __restrict__ C,
                                                    int M, int K, int Nn,
                                                    float alpha, float beta) {
  __shared__ float As[16][132];  // padded: staging writes 2-way max
  __shared__ float Bs[16][128];
  const int t = threadIdx.x;
  const int tx = t & 15, ty = t >> 4;
  const int row0 = blockIdx.y * 128, col0 = blockIdx.x * 128;
  const int ar = t >> 2;         // 0..63
  const int ak = (t & 3) << 2;   // 0,4,8,12
  const int bk = t >> 5;         // 0..7
  const int bc = (t & 31) << 2;  // 0..124
  float acc[8][8] = {};
  for (int k0 = 0; k0 < K; k0 += 16) {
    const float4 a0 = *(const float4*)&A[(row0 + ar) * K + k0 + ak];
    const float4 a1 = *(const float4*)&A[(row0 + ar + 64) * K + k0 + ak];
    const float4 b0 = *(const float4*)&Bm[(size_t)(k0 + bk) * Nn + col0 + bc];
    const float4 b1 = *(const float4*)&Bm[(size_t)(k0 + bk + 8) * Nn + col0 + bc];
    __syncthreads();
    As[ak + 0][ar] = a0.x; As[ak + 1][ar] = a0.y; As[ak + 2][ar] = a0.z; As[ak + 3][ar] = a0.w;
    As[ak + 0][ar + 64] = a1.x; As[ak + 1][ar + 64] = a1.y; As[ak + 2][ar + 64] = a1.z; As[ak + 3][ar + 64] = a1.w;
    *(float4*)&Bs[bk][bc] = b0;
    *(float4*)&Bs[bk + 8][bc] = b1;
    __syncthreads();
#pragma unroll
    for (int kk = 0; kk < 16; ++kk) {
      float ra[8], rb[8];
      *(float4*)&ra[0] = *(const float4*)&As[kk][ty << 2];
      *(float4*)&ra[4] = *(const float4*)&As[kk][64 + (ty << 2)];
      *(float4*)&rb[0] = *(const float4*)&Bs[kk][tx << 2];
      *(float4*)&rb[4] = *(const float4*)&Bs[kk][64 + (tx << 2)];
#pragma unroll
      for (int i = 0; i < 8; ++i)
#pragma unroll
        for (int j = 0; j < 8; ++j) acc[i][j] = fmaf(ra[i], rb[j], acc[i][j]);
    }
  }
#pragma unroll
  for (int gi = 0; gi < 2; ++gi)
#pragma unroll
    for (int i = 0; i < 4; ++i) {
      const int r = row0 + gi * 64 + (ty << 2) + i;
#pragma unroll
      for (int gj = 0; gj < 2; ++gj) {
        const int c = col0 + gj * 64 + (tx << 2);
        float4 o;
        o.x = alpha * acc[gi * 4 + i][gj * 4 + 0];
        o.y = alpha * acc[gi * 4 + i][gj * 4 + 1];
        o.z = alpha * acc[gi * 4 + i][gj * 4 + 2];
        o.w = alpha * acc[gi * 4 + i][gj * 4 + 3];
        if (HAS_C) {
          const float4 ci = *(const float4*)&Cin[(size_t)r * Nn + c];
          o.x = fmaf(beta, ci.x, o.x); o.y = fmaf(beta, ci.y, o.y);
          o.z = fmaf(beta, ci.z, o.z); o.w = fmaf(beta, ci.w, o.w);
        }
        *(float4*)&C[(size_t)r * Nn + c] = o;
      }
    }
}

// ---------- per-node gate: z_r = sigmoid(Xn @ Wn + bias); z->zb, r*state->rs ----------
__global__ __launch_bounds__(256) void pernode_gate_kernel(
    const float* __restrict__ T0, const float* __restrict__ Y1, const float* __restrict__ Y2,
    const float* __restrict__ emb, const float* __restrict__ Wg, const float* __restrict__ bg,
    const float* __restrict__ state, float* __restrict__ zb, float* __restrict__ rs) {
  __shared__ float XkT[128][64];   // 32 KB (i-major, b contiguous)
  __shared__ float Wk[128][128];   // 64 KB
  __shared__ float embn[E_];
  __shared__ float bias[128];
  const int n = blockIdx.x;
  const int t = threadIdx.x;
  if (t < E_) embn[t] = emb[n * E_ + t];
  __syncthreads();
  if (t < 128) {
    float a = 0.f;
#pragma unroll
    for (int d = 0; d < E_; ++d) a = fmaf(embn[d], bg[d * 128 + t], a);
    bias[t] = a;
  }
  const int tx = t & 15, ty = t >> 4;
  float acc[4][8] = {};
  const float* Xs[3] = {T0 + n * 8192, Y1 + n * 8192, Y2 + n * 8192};
#pragma unroll
  for (int k = 0; k < 3; ++k) {
    __syncthreads();
    {  // stage X_k transposed: XkT[i][b]
      const int b = t & 63, i0 = (t >> 6) * 32;
      const float* src = Xs[k] + b * 128 + i0;
#pragma unroll
      for (int i = 0; i < 32; ++i) XkT[i0 + i][b] = src[i];
    }
    {  // W_k[i][o] = sum_d emb[n,d] * Wg[d,k,i,o]
      const int o4 = (t & 31) << 2;
      const int i0 = (t >> 5) * 16;
      const float* wbase = Wg + k * 16384 + o4;
#pragma unroll
      for (int ii = 0; ii < 16; ++ii) {
        const int i = i0 + ii;
        float4 w = {0.f, 0.f, 0.f, 0.f};
#pragma unroll
        for (int d = 0; d < E_; ++d) {
          const float4 wp = *(const float4*)&wbase[d * 49152 + i * 128];
          const float ev = embn[d];
          w.x = fmaf(ev, wp.x, w.x); w.y = fmaf(ev, wp.y, w.y);
          w.z = fmaf(ev, wp.z, w.z); w.w = fmaf(ev, wp.w, w.w);
        }
        *(float4*)&Wk[i][o4] = w;
      }
    }
    __syncthreads();
#pragma unroll 4
    for (int i = 0; i < 128; ++i) {
      float xv[4], w[8];
      *(float4*)&xv[0] = *(const float4*)&XkT[i][ty << 2];
      *(float4*)&w[0] = *(const float4*)&Wk[i][tx << 2];
      *(float4*)&w[4] = *(const float4*)&Wk[i][64 + (tx << 2)];
#pragma unroll
      for (int bi = 0; bi < 4; ++bi)
#pragma unroll
        for (int oj = 0; oj < 8; ++oj) acc[bi][oj] = fmaf(xv[bi], w[oj], acc[bi][oj]);
    }
  }
#pragma unroll
  for (int bi = 0; bi < 4; ++bi) {
    const int b = (ty << 2) + bi;
    const int base = (b << 16) + (n << 6) + (tx << 2);
    const float4 st = *(const float4*)&state[base];
    float4 z, rr;
    z.x = sigmoidf_(acc[bi][0] + bias[(tx << 2) + 0]);
    z.y = sigmoidf_(acc[bi][1] + bias[(tx << 2) + 1]);
    z.z = sigmoidf_(acc[bi][2] + bias[(tx << 2) + 2]);
    z.w = sigmoidf_(acc[bi][3] + bias[(tx << 2) + 3]);
    rr.x = sigmoidf_(acc[bi][4] + bias[64 + (tx << 2) + 0]) * st.x;
    rr.y = sigmoidf_(acc[bi][5] + bias[64 + (tx << 2) + 1]) * st.y;
    rr.z = sigmoidf_(acc[bi][6] + bias[64 + (tx << 2) + 2]) * st.z;
    rr.w = sigmoidf_(acc[bi][7] + bias[64 + (tx << 2) + 3]) * st.w;
    *(float4*)&zb[base] = z;
    *(float4*)&rs[base] = rr;
  }
}

// ---------- per-node update: h=tanh(Xn@Wn+b); out = z*state + (1-z)*h ----------
__global__ __launch_bounds__(256) void pernode_update_kernel(
    const float* __restrict__ T0, const float* __restrict__ Y1, const float* __restrict__ Y2,
    const float* __restrict__ emb, const float* __restrict__ Wu, const float* __restrict__ bu,
    const float* __restrict__ state, const float* __restrict__ zb, float* __restrict__ out) {
  __shared__ float XkT[128][64];
  __shared__ float Wk[128][64];
  __shared__ float embn[E_];
  __shared__ float bias[64];
  const int n = blockIdx.x;
  const int t = threadIdx.x;
  if (t < E_) embn[t] = emb[n * E_ + t];
  __syncthreads();
  if (t < 64) {
    float a = 0.f;
#pragma unroll
    for (int d = 0; d < E_; ++d) a = fmaf(embn[d], bu[d * 64 + t], a);
    bias[t] = a;
  }
  const int tx = t & 15, ty = t >> 4;
  float acc[4][4] = {};
  const float* Xs[3] = {T0 + n * 8192, Y1 + n * 8192, Y2 + n * 8192};
#pragma unroll
  for (int k = 0; k < 3; ++k) {
    __syncthreads();
    {
      const int b = t & 63, i0 = (t >> 6) * 32;
      const float* src = Xs[k] + b * 128 + i0;
#pragma unroll
      for (int i = 0; i < 32; ++i) XkT[i0 + i][b] = src[i];
    }
    {
      const int o4 = (t & 15) << 2;
      const int i0 = (t >> 4) * 8;
      const float* wbase = Wu + k * 8192 + o4;
#pragma unroll
      for (int ii = 0; ii < 8; ++ii) {
        const int i = i0 + ii;
        float4 w = {0.f, 0.f, 0.f, 0.f};
#pragma unroll
        for (int d = 0; d < E_; ++d) {
          const float4 wp = *(const float4*)&wbase[d * 24576 + i * 64];
          const float ev = embn[d];
          w.x = fmaf(ev, wp.x, w.x); w.y = fmaf(ev, wp.y, w.y);
          w.z = fmaf(ev, wp.z, w.z); w.w = fmaf(ev, wp.w, w.w);
        }
        *(float4*)&Wk[i][o4] = w;
      }
    }
    __syncthreads();
#pragma unroll 4
    for (int i = 0; i < 128; ++i) {
      float xv[4], w[4];
      *(float4*)&xv[0] = *(const float4*)&XkT[i][ty << 2];
      *(float4*)&w[0] = *(const float4*)&Wk[i][tx << 2];
#pragma unroll
      for (int bi = 0; bi < 4; ++bi)
#pragma unroll
        for (int oj = 0; oj < 4; ++oj) acc[bi][oj] = fmaf(xv[bi], w[oj], acc[bi][oj]);
    }
  }
#pragma unroll
  for (int bi = 0; bi < 4; ++bi) {
    const int b = (ty << 2) + bi;
    const int base = (b << 16) + (n << 6) + (tx << 2);
    const float4 st = *(const float4*)&state[base];
    const float4 zv = *(const float4*)&zb[base];
    float4 o;
    o.x = zv.x * st.x + (1.f - zv.x) * tanhf(acc[bi][0] + bias[(tx << 2) + 0]);
    o.y = zv.y * st.y + (1.f - zv.y) * tanhf(acc[bi][1] + bias[(tx << 2) + 1]);
    o.z = zv.z * st.z + (1.f - zv.z) * tanhf(acc[bi][2] + bias[(tx << 2) + 2]);
    o.w = zv.w * st.w + (1.f - zv.w) * tanhf(acc[bi][3] + bias[(tx << 2) + 3]);
    *(float4*)&out[base] = o;
  }
}

extern "C" void kernel_launch(void* const* d_in, const int* in_sizes, int n_in,
                              void* d_out, int out_size, void* d_ws, size_t ws_size,
                              hipStream_t stream) {
  const float* x     = (const float*)d_in[0];
  const float* state = (const float*)d_in[1];
  const float* emb   = (const float*)d_in[2];
  const float* Wg    = (const float*)d_in[3];
  const float* bg    = (const float*)d_in[4];
  const float* Wu    = (const float*)d_in[5];
  const float* bu    = (const float*)d_in[6];
  float* out = (float*)d_out;
  float* ws  = (float*)d_ws;

  float* A  = ws;               // 1M floats   (4 MB)
  float* T0 = A  + (1 << 20);   // 8M floats   (32 MB)  (N, B, 128)
  float* Y1 = T0 + (8 << 20);   // 8M
  float* Y2 = Y1 + (8 << 20);   // 8M
  float* rs = Y2 + (8 << 20);   // 4M  r*state (B, N, 64)
  float* zb = out;              // z lives in d_out; final kernel reads+overwrites in place

  dim3 g(64, 8);  // (Nn/128, M/128)

  compute_A_kernel<<<N_, 256, 0, stream>>>(emb, A);

  // ---- gate pass ----
  build_T0_kernel<<<32768, 256, 0, stream>>>(x, state, T0);
  sgemm_kernel<0><<<g, 256, 0, stream>>>(A, T0, nullptr, Y1, 1024, 1024, 8192, 1.f, 0.f);
  sgemm_kernel<1><<<g, 256, 0, stream>>>(A, Y1, T0, Y2, 1024, 1024, 8192, 2.f, -1.f);
  pernode_gate_kernel<<<N_, 256, 0, stream>>>(T0, Y1, Y2, emb, Wg, bg, state, zb, rs);

  // ---- update pass ----
  build_T0_kernel<<<32768, 256, 0, stream>>>(x, rs, T0);
  sgemm_kernel<0><<<g, 256, 0, stream>>>(A, T0, nullptr, Y1, 1024, 1024, 8192, 1.f, 0.f);
  sgemm_kernel<1><<<g, 256, 0, stream>>>(A, Y1, T0, Y2, 1024, 1024, 8192, 2.f, -1.f);
  pernode_update_kernel<<<N_, 256, 0, stream>>>(T0, Y1, Y2, emb, Wu, bu, state, zb, out);
}

// Round 2
// 1092.812 us; speedup vs baseline: 1.2929x; 1.2929x over previous
//
#include <hip/hip_runtime.h>
#include <hip/hip_bf16.h>
#include <math.h>

#define B_ 64
#define N_ 1024
#define E_ 16

__device__ __forceinline__ float sigmoidf_(float x) {
  return 1.0f / (1.0f + __expf(-x));
}
__device__ __forceinline__ unsigned short f2bf(float f) {  // RNE
  unsigned int u = __float_as_uint(f);
  u = (u + 0x7fffu + ((u >> 16) & 1u)) >> 16;
  return (unsigned short)u;
}
__device__ __forceinline__ float bflo(unsigned int p) { return __uint_as_float(p << 16); }
__device__ __forceinline__ float bfhi(unsigned int p) { return __uint_as_float(p & 0xffff0000u); }

// ---------- A = softmax(relu(emb @ emb^T), axis=1) ----------
__global__ __launch_bounds__(256) void compute_A_kernel(const float* __restrict__ emb,
                                                        float* __restrict__ A) {
  __shared__ float embn[E_];
  __shared__ float red[256];
  const int n = blockIdx.x;
  const int t = threadIdx.x;
  if (t < E_) embn[t] = emb[n * E_ + t];
  __syncthreads();
  float s[4];
#pragma unroll
  for (int j = 0; j < 4; ++j) {
    const int m = j * 256 + t;
    const float* em = emb + m * E_;
    float acc = 0.f;
#pragma unroll
    for (int d = 0; d < E_; ++d) acc = fmaf(embn[d], em[d], acc);
    s[j] = fmaxf(acc, 0.f);
  }
  float mx = fmaxf(fmaxf(s[0], s[1]), fmaxf(s[2], s[3]));
  red[t] = mx;
  __syncthreads();
  for (int off = 128; off > 0; off >>= 1) {
    if (t < off) red[t] = fmaxf(red[t], red[t + off]);
    __syncthreads();
  }
  mx = red[0];
  __syncthreads();
  float e[4], lsum = 0.f;
#pragma unroll
  for (int j = 0; j < 4; ++j) { e[j] = __expf(s[j] - mx); lsum += e[j]; }
  red[t] = lsum;
  __syncthreads();
  for (int off = 128; off > 0; off >>= 1) {
    if (t < off) red[t] += red[t + off];
    __syncthreads();
  }
  const float inv = 1.0f / red[0];
#pragma unroll
  for (int j = 0; j < 4; ++j) A[n * N_ + j * 256 + t] = e[j] * inv;
}

// ---------- Wn[n][J] (bf16) = sum_d emb[n][d] * Wp[d][J] ----------
template <int J_TOTAL>
__global__ __launch_bounds__(256) void wcombine_kernel(const float* __restrict__ emb,
                                                       const float* __restrict__ Wp,
                                                       unsigned short* __restrict__ Wn) {
  __shared__ float es[8][E_];
  const int t = threadIdx.x;
  const int n0 = blockIdx.y * 8;
  if (t < 8 * E_) es[t >> 4][t & 15] = emb[n0 * E_ + t];
  __syncthreads();
  const int j = blockIdx.x * 1024 + t * 4;
  float4 acc[8] = {};
#pragma unroll 4
  for (int d = 0; d < E_; ++d) {
    const float4 w = *(const float4*)&Wp[(size_t)d * J_TOTAL + j];
#pragma unroll
    for (int g = 0; g < 8; ++g) {
      const float e = es[g][d];
      acc[g].x = fmaf(e, w.x, acc[g].x);
      acc[g].y = fmaf(e, w.y, acc[g].y);
      acc[g].z = fmaf(e, w.z, acc[g].z);
      acc[g].w = fmaf(e, w.w, acc[g].w);
    }
  }
#pragma unroll
  for (int g = 0; g < 8; ++g) {
    ushort4 o;
    o.x = f2bf(acc[g].x); o.y = f2bf(acc[g].y);
    o.z = f2bf(acc[g].z); o.w = f2bf(acc[g].w);
    *(ushort4*)&Wn[(size_t)(n0 + g) * J_TOTAL + j] = o;
  }
}

// ---------- T0[n][b][c] = c<64 ? xa[b,n,c] : xb[b,n,c-64] ----------
__global__ __launch_bounds__(256) void build_T0_kernel(const float* __restrict__ xa,
                                                       const float* __restrict__ xb,
                                                       float* __restrict__ T0) {
  const int idx = blockIdx.x * 256 + threadIdx.x;
  const int c = idx & 127;
  const int b = (idx >> 7) & 63;
  const int n = idx >> 13;
  const int src = (b << 16) + (n << 6);
  T0[idx] = (c < 64) ? xa[src + c] : xb[src + c - 64];
}

// ---------- C = alpha*A@B (+ beta*Cin) ; 128x128 tile, 8x8 microtile ----------
template <int HAS_C>
__global__ __launch_bounds__(256) void sgemm_kernel(const float* __restrict__ A,
                                                    const float* __restrict__ Bm,
                                                    const float* __restrict__ Cin,
                                                    float* __restrict__ C,
                                                    int M, int K, int Nn,
                                                    float alpha, float beta) {
  __shared__ float As[16][132];
  __shared__ float Bs[16][128];
  const int t = threadIdx.x;
  const int tx = t & 15, ty = t >> 4;
  const int row0 = blockIdx.y * 128, col0 = blockIdx.x * 128;
  const int ar = t >> 2;
  const int ak = (t & 3) << 2;
  const int bk = t >> 5;
  const int bc = (t & 31) << 2;
  float acc[8][8] = {};
  for (int k0 = 0; k0 < K; k0 += 16) {
    const float4 a0 = *(const float4*)&A[(row0 + ar) * K + k0 + ak];
    const float4 a1 = *(const float4*)&A[(row0 + ar + 64) * K + k0 + ak];
    const float4 b0 = *(const float4*)&Bm[(size_t)(k0 + bk) * Nn + col0 + bc];
    const float4 b1 = *(const float4*)&Bm[(size_t)(k0 + bk + 8) * Nn + col0 + bc];
    __syncthreads();
    As[ak + 0][ar] = a0.x; As[ak + 1][ar] = a0.y; As[ak + 2][ar] = a0.z; As[ak + 3][ar] = a0.w;
    As[ak + 0][ar + 64] = a1.x; As[ak + 1][ar + 64] = a1.y; As[ak + 2][ar + 64] = a1.z; As[ak + 3][ar + 64] = a1.w;
    *(float4*)&Bs[bk][bc] = b0;
    *(float4*)&Bs[bk + 8][bc] = b1;
    __syncthreads();
#pragma unroll
    for (int kk = 0; kk < 16; ++kk) {
      float ra[8], rb[8];
      *(float4*)&ra[0] = *(const float4*)&As[kk][ty << 2];
      *(float4*)&ra[4] = *(const float4*)&As[kk][64 + (ty << 2)];
      *(float4*)&rb[0] = *(const float4*)&Bs[kk][tx << 2];
      *(float4*)&rb[4] = *(const float4*)&Bs[kk][64 + (tx << 2)];
#pragma unroll
      for (int i = 0; i < 8; ++i)
#pragma unroll
        for (int j = 0; j < 8; ++j) acc[i][j] = fmaf(ra[i], rb[j], acc[i][j]);
    }
  }
#pragma unroll
  for (int gi = 0; gi < 2; ++gi)
#pragma unroll
    for (int i = 0; i < 4; ++i) {
      const int r = row0 + gi * 64 + (ty << 2) + i;
#pragma unroll
      for (int gj = 0; gj < 2; ++gj) {
        const int c = col0 + gj * 64 + (tx << 2);
        float4 o;
        o.x = alpha * acc[gi * 4 + i][gj * 4 + 0];
        o.y = alpha * acc[gi * 4 + i][gj * 4 + 1];
        o.z = alpha * acc[gi * 4 + i][gj * 4 + 2];
        o.w = alpha * acc[gi * 4 + i][gj * 4 + 3];
        if (HAS_C) {
          const float4 ci = *(const float4*)&Cin[(size_t)r * Nn + c];
          o.x = fmaf(beta, ci.x, o.x); o.y = fmaf(beta, ci.y, o.y);
          o.z = fmaf(beta, ci.z, o.z); o.w = fmaf(beta, ci.w, o.w);
        }
        *(float4*)&C[(size_t)r * Nn + c] = o;
      }
    }
}

// ---------- per-node gate with precomputed bf16 weights ----------
__global__ __launch_bounds__(256) void pernode_gate_kernel(
    const float* __restrict__ T0, const float* __restrict__ Y1, const float* __restrict__ Y2,
    const unsigned short* __restrict__ Wn,  // [n][3*128][128] bf16
    const float* __restrict__ emb, const float* __restrict__ bg,
    const float* __restrict__ state, float* __restrict__ zb, float* __restrict__ rs) {
  __shared__ float XkT[128][68];  // 34.8 KB, i-major
  __shared__ float Wf[64][128];   // 32 KB half-slab
  __shared__ float embn[E_];
  __shared__ float bias[128];
  const int n = blockIdx.x;
  const int t = threadIdx.x;
  if (t < E_) embn[t] = emb[n * E_ + t];
  __syncthreads();
  if (t < 128) {
    float a = 0.f;
#pragma unroll
    for (int d = 0; d < E_; ++d) a = fmaf(embn[d], bg[d * 128 + t], a);
    bias[t] = a;
  }
  const int tx = t & 15, ty = t >> 4;
  float acc[4][8] = {};
  const float* Xs[3] = {T0 + n * 8192, Y1 + n * 8192, Y2 + n * 8192};
  const unsigned short* Wb = Wn + (size_t)n * 49152;
#pragma unroll
  for (int k = 0; k < 3; ++k) {
    __syncthreads();
    {  // stage X_k transposed (f32)
      const int b = t & 63, i0 = (t >> 6) * 32;
      const float* src = Xs[k] + b * 128 + i0;
#pragma unroll
      for (int i = 0; i < 32; ++i) XkT[i0 + i][b] = src[i];
    }
#pragma unroll
    for (int h = 0; h < 2; ++h) {
      if (h) __syncthreads();
      {  // stage W half-slab: bf16 -> f32
        const unsigned short* wsrc = Wb + k * 16384 + h * 8192;
#pragma unroll
        for (int r = 0; r < 4; ++r) {
          const int off = r * 2048 + t * 8;
          const uint4 p = *(const uint4*)&wsrc[off];
          float* dst = &Wf[0][0] + off;
          dst[0] = bflo(p.x); dst[1] = bfhi(p.x);
          dst[2] = bflo(p.y); dst[3] = bfhi(p.y);
          dst[4] = bflo(p.z); dst[5] = bfhi(p.z);
          dst[6] = bflo(p.w); dst[7] = bfhi(p.w);
        }
      }
      __syncthreads();
      const int ib = h * 64;
#pragma unroll 4
      for (int ii = 0; ii < 64; ++ii) {
        float xv[4], w[8];
        *(float4*)&xv[0] = *(const float4*)&XkT[ib + ii][ty << 2];
        *(float4*)&w[0] = *(const float4*)&Wf[ii][tx << 2];
        *(float4*)&w[4] = *(const float4*)&Wf[ii][64 + (tx << 2)];
#pragma unroll
        for (int bi = 0; bi < 4; ++bi)
#pragma unroll
          for (int oj = 0; oj < 8; ++oj) acc[bi][oj] = fmaf(xv[bi], w[oj], acc[bi][oj]);
      }
    }
  }
#pragma unroll
  for (int bi = 0; bi < 4; ++bi) {
    const int b = (ty << 2) + bi;
    const int base = (b << 16) + (n << 6) + (tx << 2);
    const float4 st = *(const float4*)&state[base];
    float4 z, rr;
    z.x = sigmoidf_(acc[bi][0] + bias[(tx << 2) + 0]);
    z.y = sigmoidf_(acc[bi][1] + bias[(tx << 2) + 1]);
    z.z = sigmoidf_(acc[bi][2] + bias[(tx << 2) + 2]);
    z.w = sigmoidf_(acc[bi][3] + bias[(tx << 2) + 3]);
    rr.x = sigmoidf_(acc[bi][4] + bias[64 + (tx << 2) + 0]) * st.x;
    rr.y = sigmoidf_(acc[bi][5] + bias[64 + (tx << 2) + 1]) * st.y;
    rr.z = sigmoidf_(acc[bi][6] + bias[64 + (tx << 2) + 2]) * st.z;
    rr.w = sigmoidf_(acc[bi][7] + bias[64 + (tx << 2) + 3]) * st.w;
    *(float4*)&zb[base] = z;
    *(float4*)&rs[base] = rr;
  }
}

// ---------- per-node update with precomputed bf16 weights ----------
__global__ __launch_bounds__(256) void pernode_update_kernel(
    const float* __restrict__ T0, const float* __restrict__ Y1, const float* __restrict__ Y2,
    const unsigned short* __restrict__ Wn,  // [n][3*128][64] bf16
    const float* __restrict__ emb, const float* __restrict__ bu,
    const float* __restrict__ state, const float* __restrict__ zb, float* __restrict__ out) {
  __shared__ float XkT[128][68];
  __shared__ float Wf[64][64];  // 16 KB half-slab
  __shared__ float embn[E_];
  __shared__ float bias[64];
  const int n = blockIdx.x;
  const int t = threadIdx.x;
  if (t < E_) embn[t] = emb[n * E_ + t];
  __syncthreads();
  if (t < 64) {
    float a = 0.f;
#pragma unroll
    for (int d = 0; d < E_; ++d) a = fmaf(embn[d], bu[d * 64 + t], a);
    bias[t] = a;
  }
  const int tx = t & 15, ty = t >> 4;
  float acc[4][4] = {};
  const float* Xs[3] = {T0 + n * 8192, Y1 + n * 8192, Y2 + n * 8192};
  const unsigned short* Wb = Wn + (size_t)n * 24576;
#pragma unroll
  for (int k = 0; k < 3; ++k) {
    __syncthreads();
    {
      const int b = t & 63, i0 = (t >> 6) * 32;
      const float* src = Xs[k] + b * 128 + i0;
#pragma unroll
      for (int i = 0; i < 32; ++i) XkT[i0 + i][b] = src[i];
    }
#pragma unroll
    for (int h = 0; h < 2; ++h) {
      if (h) __syncthreads();
      {
        const unsigned short* wsrc = Wb + k * 8192 + h * 4096;
#pragma unroll
        for (int r = 0; r < 2; ++r) {
          const int off = r * 2048 + t * 8;
          const uint4 p = *(const uint4*)&wsrc[off];
          float* dst = &Wf[0][0] + off;
          dst[0] = bflo(p.x); dst[1] = bfhi(p.x);
          dst[2] = bflo(p.y); dst[3] = bfhi(p.y);
          dst[4] = bflo(p.z); dst[5] = bfhi(p.z);
          dst[6] = bflo(p.w); dst[7] = bfhi(p.w);
        }
      }
      __syncthreads();
      const int ib = h * 64;
#pragma unroll 4
      for (int ii = 0; ii < 64; ++ii) {
        float xv[4], w[4];
        *(float4*)&xv[0] = *(const float4*)&XkT[ib + ii][ty << 2];
        *(float4*)&w[0] = *(const float4*)&Wf[ii][tx << 2];
#pragma unroll
        for (int bi = 0; bi < 4; ++bi)
#pragma unroll
          for (int oj = 0; oj < 4; ++oj) acc[bi][oj] = fmaf(xv[bi], w[oj], acc[bi][oj]);
      }
    }
  }
#pragma unroll
  for (int bi = 0; bi < 4; ++bi) {
    const int b = (ty << 2) + bi;
    const int base = (b << 16) + (n << 6) + (tx << 2);
    const float4 st = *(const float4*)&state[base];
    const float4 zv = *(const float4*)&zb[base];
    float4 o;
    o.x = zv.x * st.x + (1.f - zv.x) * tanhf(acc[bi][0] + bias[(tx << 2) + 0]);
    o.y = zv.y * st.y + (1.f - zv.y) * tanhf(acc[bi][1] + bias[(tx << 2) + 1]);
    o.z = zv.z * st.z + (1.f - zv.z) * tanhf(acc[bi][2] + bias[(tx << 2) + 2]);
    o.w = zv.w * st.w + (1.f - zv.w) * tanhf(acc[bi][3] + bias[(tx << 2) + 3]);
    *(float4*)&out[base] = o;
  }
}

extern "C" void kernel_launch(void* const* d_in, const int* in_sizes, int n_in,
                              void* d_out, int out_size, void* d_ws, size_t ws_size,
                              hipStream_t stream) {
  const float* x     = (const float*)d_in[0];
  const float* state = (const float*)d_in[1];
  const float* emb   = (const float*)d_in[2];
  const float* Wg    = (const float*)d_in[3];
  const float* bg    = (const float*)d_in[4];
  const float* Wu    = (const float*)d_in[5];
  const float* bu    = (const float*)d_in[6];
  float* out = (float*)d_out;
  float* ws  = (float*)d_ws;

  float* A  = ws;               // 1M floats   (4 MB)
  float* T0 = A  + (1 << 20);   // 8M floats   (32 MB)  (N, B, 128)
  float* Y1 = T0 + (8 << 20);   // 8M
  float* Y2 = Y1 + (8 << 20);   // 8M
  float* rs = Y2 + (8 << 20);   // 4M  r*state (B, N, 64)
  unsigned short* WnB = (unsigned short*)(rs + (4 << 20));  // 50.3M bf16 (100.7 MB)
  float* zb = out;

  dim3 g(64, 8);

  compute_A_kernel<<<N_, 256, 0, stream>>>(emb, A);
  wcombine_kernel<49152><<<dim3(48, 128), 256, 0, stream>>>(emb, Wg, WnB);

  // ---- gate pass ----
  build_T0_kernel<<<32768, 256, 0, stream>>>(x, state, T0);
  sgemm_kernel<0><<<g, 256, 0, stream>>>(A, T0, nullptr, Y1, 1024, 1024, 8192, 1.f, 0.f);
  sgemm_kernel<1><<<g, 256, 0, stream>>>(A, Y1, T0, Y2, 1024, 1024, 8192, 2.f, -1.f);
  pernode_gate_kernel<<<N_, 256, 0, stream>>>(T0, Y1, Y2, WnB, emb, bg, state, zb, rs);

  // ---- update pass ----
  wcombine_kernel<24576><<<dim3(24, 128), 256, 0, stream>>>(emb, Wu, WnB);
  build_T0_kernel<<<32768, 256, 0, stream>>>(x, rs, T0);
  sgemm_kernel<0><<<g, 256, 0, stream>>>(A, T0, nullptr, Y1, 1024, 1024, 8192, 1.f, 0.f);
  sgemm_kernel<1><<<g, 256, 0, stream>>>(A, Y1, T0, Y2, 1024, 1024, 8192, 2.f, -1.f);
  pernode_update_kernel<<<N_, 256, 0, stream>>>(T0, Y1, Y2, WnB, emb, bu, state, zb, out);
}

// Round 3
// 491.166 us; speedup vs baseline: 2.8767x; 2.2249x over previous
//
#include <hip/hip_runtime.h>
#include <hip/hip_bf16.h>
#include <math.h>

#define B_ 64
#define N_ 1024
#define E_ 16

typedef unsigned short ushort_t;
typedef __attribute__((ext_vector_type(8))) short bf16x8;
typedef __attribute__((ext_vector_type(4))) float f32x4;

__device__ __forceinline__ float sigmoidf_(float x) {
  return 1.0f / (1.0f + __expf(-x));
}
__device__ __forceinline__ ushort_t f2bf(float f) {  // RNE
  unsigned int u = __float_as_uint(f);
  u = (u + 0x7fffu + ((u >> 16) & 1u)) >> 16;
  return (ushort_t)u;
}
__device__ __forceinline__ float bf2f(ushort_t h) { return __uint_as_float((unsigned)h << 16); }
__device__ __forceinline__ void split_bf(float x, ushort_t& h, ushort_t& l) {
  h = f2bf(x);
  l = f2bf(x - bf2f(h));
}
__device__ __forceinline__ void gload16(const void* g, void* l) {
  __builtin_amdgcn_global_load_lds(
      (const __attribute__((address_space(1))) unsigned int*)g,
      (__attribute__((address_space(3))) unsigned int*)l, 16, 0, 0);
}

// ---------- A = softmax(relu(emb@emb^T)) -> hi/lo bf16 [n][m] ----------
__global__ __launch_bounds__(256) void compute_A_kernel(const float* __restrict__ emb,
                                                        ushort_t* __restrict__ Ah,
                                                        ushort_t* __restrict__ Al) {
  __shared__ float embn[E_];
  __shared__ float red[256];
  const int n = blockIdx.x;
  const int t = threadIdx.x;
  if (t < E_) embn[t] = emb[n * E_ + t];
  __syncthreads();
  float s[4];
#pragma unroll
  for (int j = 0; j < 4; ++j) {
    const int m = j * 256 + t;
    const float* em = emb + m * E_;
    float acc = 0.f;
#pragma unroll
    for (int d = 0; d < E_; ++d) acc = fmaf(embn[d], em[d], acc);
    s[j] = fmaxf(acc, 0.f);
  }
  float mx = fmaxf(fmaxf(s[0], s[1]), fmaxf(s[2], s[3]));
  red[t] = mx;
  __syncthreads();
  for (int off = 128; off > 0; off >>= 1) {
    if (t < off) red[t] = fmaxf(red[t], red[t + off]);
    __syncthreads();
  }
  mx = red[0];
  __syncthreads();
  float e[4], lsum = 0.f;
#pragma unroll
  for (int j = 0; j < 4; ++j) { e[j] = __expf(s[j] - mx); lsum += e[j]; }
  red[t] = lsum;
  __syncthreads();
  for (int off = 128; off > 0; off >>= 1) {
    if (t < off) red[t] += red[t + off];
    __syncthreads();
  }
  const float inv = 1.0f / red[0];
#pragma unroll
  for (int j = 0; j < 4; ++j) {
    const float v = e[j] * inv;
    ushort_t h, l;
    split_bf(v, h, l);
    Ah[n * N_ + j * 256 + t] = h;
    Al[n * N_ + j * 256 + t] = l;
  }
}

// ---------- cat(xA,xB)[b][n][c] -> T0t hi/lo [(b*128+c)][n] ----------
__global__ __launch_bounds__(256) void build_T0t_kernel(const float* __restrict__ xA,
                                                        const float* __restrict__ xB,
                                                        ushort_t* __restrict__ Th,
                                                        ushort_t* __restrict__ Tl) {
  __shared__ float tile[128][129];  // [c][n-local]
  const int t = threadIdx.x;
  const int b = blockIdx.y;
  const int n0 = blockIdx.x << 7;
  const int c4 = (t & 31) << 2, nl = t >> 5;
#pragma unroll
  for (int p = 0; p < 16; ++p) {
    const int n = nl + (p << 3);
    const float4 v = (c4 < 64)
        ? *(const float4*)&xA[((size_t)b << 16) + ((size_t)(n0 + n) << 6) + c4]
        : *(const float4*)&xB[((size_t)b << 16) + ((size_t)(n0 + n) << 6) + c4 - 64];
    tile[c4 + 0][n] = v.x; tile[c4 + 1][n] = v.y;
    tile[c4 + 2][n] = v.z; tile[c4 + 3][n] = v.w;
  }
  __syncthreads();
  const int c = t >> 1, nc = (t & 1) << 6;
  const size_t obase = ((size_t)(b << 7) + c) * 1024 + n0 + nc;
#pragma unroll
  for (int u = 0; u < 64; u += 4) {
    ushort4 h, l;
    split_bf(tile[c][nc + u + 0], h.x, l.x);
    split_bf(tile[c][nc + u + 1], h.y, l.y);
    split_bf(tile[c][nc + u + 2], h.z, l.z);
    split_bf(tile[c][nc + u + 3], h.w, l.w);
    *(ushort4*)&Th[obase + u] = h;
    *(ushort4*)&Tl[obase + u] = l;
  }
}

// ---------- MFMA split-bf16 GEMM: D[n][j] = sum_m Aop[n][m] * Bop[j][m] ----------
// PHASE==1: Yf = acc ; also write hi/lo transposed Yt[j][n]
// PHASE==0: Yf = 2*acc - (T0th+T0tl)[j][n]
template <int PHASE>
__global__ __launch_bounds__(256, 2) void mfma_gemm_kernel(
    const ushort_t* __restrict__ Ah, const ushort_t* __restrict__ Al,   // [1024][1024]
    const ushort_t* __restrict__ Bh, const ushort_t* __restrict__ Bl,   // [8192][1024]
    const ushort_t* __restrict__ T0th, const ushort_t* __restrict__ T0tl,
    float* __restrict__ Yf, ushort_t* __restrict__ Yth, ushort_t* __restrict__ Ytl) {
  __shared__ ushort_t Ah_s[128 * 64], Al_s[128 * 64], Bh_s[128 * 64], Bl_s[128 * 64];
  const int t = threadIdx.x;
  const int wave = t >> 6, lane = t & 63;
  const int n0 = blockIdx.y << 7;   // 8
  const int j0 = blockIdx.x << 7;   // 64
  const int wr = wave >> 1, wc = wave & 1;
  const int fr = lane & 15, fk = lane >> 4;

  f32x4 acc[4][4];
#pragma unroll
  for (int i = 0; i < 4; ++i)
#pragma unroll
    for (int j = 0; j < 4; ++j) acc[i][j] = (f32x4){0.f, 0.f, 0.f, 0.f};

  // staging geometry: per array 128 rows x 128B; instr q covers rows [q*8, q*8+8)
  const int rsub = lane >> 3;          // row within 8-group
  const int cp = lane & 7;             // dest 16B chunk within row
  const int selem = (((cp << 4) ^ (rsub << 4)) >> 1);  // pre-swizzled src elem offset

  for (int k0 = 0; k0 < 1024; k0 += 64) {
    __syncthreads();
#pragma unroll
    for (int i = 0; i < 4; ++i) {
      const int q = (wave << 2) + i;
      const int row = (q << 3) + rsub;
      const int lo = (q << 9) + lane * 8;  // ushort units (=q*1024B + lane*16B)
      const size_t ga = (size_t)(n0 + row) * 1024 + k0 + selem;
      const size_t gb = (size_t)(j0 + row) * 1024 + k0 + selem;
      gload16(Ah + ga, Ah_s + lo);
      gload16(Al + ga, Al_s + lo);
      gload16(Bh + gb, Bh_s + lo);
      gload16(Bl + gb, Bl_s + lo);
    }
    __syncthreads();
#pragma unroll
    for (int ks = 0; ks < 2; ++ks) {
      bf16x8 ah[4], al[4], bh[4], bl[4];
#pragma unroll
      for (int mi = 0; mi < 4; ++mi) {
        const int r = (wr << 6) + (mi << 4) + fr;
        const int kb = ((ks << 6) + (fk << 4)) ^ ((r & 7) << 4);
        ah[mi] = *(const bf16x8*)((const char*)Ah_s + r * 128 + kb);
        al[mi] = *(const bf16x8*)((const char*)Al_s + r * 128 + kb);
      }
#pragma unroll
      for (int nj = 0; nj < 4; ++nj) {
        const int r = (wc << 6) + (nj << 4) + fr;
        const int kb = ((ks << 6) + (fk << 4)) ^ ((r & 7) << 4);
        bh[nj] = *(const bf16x8*)((const char*)Bh_s + r * 128 + kb);
        bl[nj] = *(const bf16x8*)((const char*)Bl_s + r * 128 + kb);
      }
#pragma unroll
      for (int mi = 0; mi < 4; ++mi)
#pragma unroll
        for (int nj = 0; nj < 4; ++nj) {
          acc[mi][nj] = __builtin_amdgcn_mfma_f32_16x16x32_bf16(ah[mi], bh[nj], acc[mi][nj], 0, 0, 0);
          acc[mi][nj] = __builtin_amdgcn_mfma_f32_16x16x32_bf16(ah[mi], bl[nj], acc[mi][nj], 0, 0, 0);
          acc[mi][nj] = __builtin_amdgcn_mfma_f32_16x16x32_bf16(al[mi], bh[nj], acc[mi][nj], 0, 0, 0);
        }
    }
  }

#pragma unroll
  for (int mi = 0; mi < 4; ++mi) {
    const int nb = n0 + (wr << 6) + (mi << 4) + (fk << 2);
#pragma unroll
    for (int nj = 0; nj < 4; ++nj) {
      const int j = j0 + (wc << 6) + (nj << 4) + fr;
      const f32x4 v = acc[mi][nj];
      if (PHASE == 1) {
#pragma unroll
        for (int r = 0; r < 4; ++r) Yf[(size_t)(nb + r) * 8192 + j] = v[r];
        ushort4 h, l;
        split_bf(v[0], h.x, l.x); split_bf(v[1], h.y, l.y);
        split_bf(v[2], h.z, l.z); split_bf(v[3], h.w, l.w);
        *(ushort4*)&Yth[(size_t)j * 1024 + nb] = h;
        *(ushort4*)&Ytl[(size_t)j * 1024 + nb] = l;
      } else {
        const ushort4 th = *(const ushort4*)&T0th[(size_t)j * 1024 + nb];
        const ushort4 tl = *(const ushort4*)&T0tl[(size_t)j * 1024 + nb];
        float t0r[4];
        t0r[0] = bf2f(th.x) + bf2f(tl.x); t0r[1] = bf2f(th.y) + bf2f(tl.y);
        t0r[2] = bf2f(th.z) + bf2f(tl.z); t0r[3] = bf2f(th.w) + bf2f(tl.w);
#pragma unroll
        for (int r = 0; r < 4; ++r) Yf[(size_t)(nb + r) * 8192 + j] = 2.0f * v[r] - t0r[r];
      }
    }
  }
}

// ---------- Wn[n][24576] (bf16) = sum_d emb[n][d] * Wp[d][k][i][o0+o], o in [0,64) ----------
template <int OW_SRC>
__global__ __launch_bounds__(256) void wcombine_half_kernel(const float* __restrict__ emb,
                                                            const float* __restrict__ Wp,
                                                            int o0,
                                                            ushort_t* __restrict__ Wn) {
  __shared__ float es[8][E_];
  const int t = threadIdx.x;
  const int n0 = blockIdx.y * 8;
  if (t < 8 * E_) es[t >> 4][t & 15] = emb[n0 * E_ + t];
  __syncthreads();
  const int j = blockIdx.x * 1024 + t * 4;          // output index within node
  const int k = j >> 13, rem = j & 8191;
  const int i = rem >> 6, o = rem & 63;
  const size_t srcj = (size_t)(k * 128 + i) * OW_SRC + o0 + o;
  const size_t dstr = (size_t)3 * 128 * OW_SRC;
  float4 acc[8] = {};
#pragma unroll 4
  for (int d = 0; d < E_; ++d) {
    const float4 w = *(const float4*)&Wp[d * dstr + srcj];
#pragma unroll
    for (int g = 0; g < 8; ++g) {
      const float e = es[g][d];
      acc[g].x = fmaf(e, w.x, acc[g].x);
      acc[g].y = fmaf(e, w.y, acc[g].y);
      acc[g].z = fmaf(e, w.z, acc[g].z);
      acc[g].w = fmaf(e, w.w, acc[g].w);
    }
  }
#pragma unroll
  for (int g = 0; g < 8; ++g) {
    ushort4 o4;
    o4.x = f2bf(acc[g].x); o4.y = f2bf(acc[g].y);
    o4.z = f2bf(acc[g].z); o4.w = f2bf(acc[g].w);
    *(ushort4*)&Wn[(size_t)(n0 + g) * 24576 + j] = o4;
  }
}

// ---------- per-node 64-output contraction + GRU epilogue ----------
// MODE 0: dst = sigmoid(acc+bias)                  (z -> d_out)
// MODE 1: dst = sigmoid(acc+bias) * state          (rs)
// MODE 2: dst = zb*state + (1-zb)*tanh(acc+bias)   (final out)
template <int MODE>
__global__ __launch_bounds__(256) void pernode64_kernel(
    const float* __restrict__ xA, const float* __restrict__ xB,
    const float* __restrict__ Y1f, const float* __restrict__ Y2f,
    const ushort_t* __restrict__ Wn,   // [n][3*128*64] bf16
    const float* __restrict__ emb, const float* __restrict__ bsrc, int bstride,
    const float* __restrict__ state, const float* __restrict__ zb,
    float* __restrict__ dst) {
  __shared__ float XkT[128][68];
  __shared__ float Wf[64][64];
  __shared__ float embn[E_];
  __shared__ float bias[64];
  const int n = blockIdx.x;
  const int t = threadIdx.x;
  if (t < E_) embn[t] = emb[n * E_ + t];
  __syncthreads();
  if (t < 64) {
    float a = 0.f;
#pragma unroll
    for (int d = 0; d < E_; ++d) a = fmaf(embn[d], bsrc[d * bstride + t], a);
    bias[t] = a;
  }
  const int tx = t & 15, ty = t >> 4;
  float acc[4][4] = {};
  const ushort_t* Wb = Wn + (size_t)n * 24576;
#pragma unroll
  for (int k = 0; k < 3; ++k) {
    __syncthreads();
    {  // stage X_k transposed: XkT[i][b]
      const int b = t & 63, i0 = (t >> 6) * 32;
      const float* src;
      if (k == 0)
        src = (i0 < 64) ? xA + ((size_t)b << 16) + ((size_t)n << 6) + i0
                        : xB + ((size_t)b << 16) + ((size_t)n << 6) + i0 - 64;
      else if (k == 1)
        src = Y1f + (size_t)n * 8192 + b * 128 + i0;
      else
        src = Y2f + (size_t)n * 8192 + b * 128 + i0;
#pragma unroll
      for (int i = 0; i < 32; ++i) XkT[i0 + i][b] = src[i];
    }
#pragma unroll
    for (int h = 0; h < 2; ++h) {
      if (h) __syncthreads();
      {  // stage W half-slab bf16 -> f32
        const ushort_t* wsrc = Wb + k * 8192 + h * 4096;
#pragma unroll
        for (int r = 0; r < 2; ++r) {
          const int off = r * 2048 + t * 8;
          const uint4 p = *(const uint4*)&wsrc[off];
          float* dstp = &Wf[0][0] + off;
          dstp[0] = bf2f((ushort_t)(p.x & 0xffff)); dstp[1] = bf2f((ushort_t)(p.x >> 16));
          dstp[2] = bf2f((ushort_t)(p.y & 0xffff)); dstp[3] = bf2f((ushort_t)(p.y >> 16));
          dstp[4] = bf2f((ushort_t)(p.z & 0xffff)); dstp[5] = bf2f((ushort_t)(p.z >> 16));
          dstp[6] = bf2f((ushort_t)(p.w & 0xffff)); dstp[7] = bf2f((ushort_t)(p.w >> 16));
        }
      }
      __syncthreads();
      const int ib = h * 64;
#pragma unroll 4
      for (int ii = 0; ii < 64; ++ii) {
        float xv[4], w[4];
        *(float4*)&xv[0] = *(const float4*)&XkT[ib + ii][ty << 2];
        *(float4*)&w[0] = *(const float4*)&Wf[ii][tx << 2];
#pragma unroll
        for (int bi = 0; bi < 4; ++bi)
#pragma unroll
          for (int oj = 0; oj < 4; ++oj) acc[bi][oj] = fmaf(xv[bi], w[oj], acc[bi][oj]);
      }
    }
  }
#pragma unroll
  for (int bi = 0; bi < 4; ++bi) {
    const int b = (ty << 2) + bi;
    const size_t base = ((size_t)b << 16) + ((size_t)n << 6) + (tx << 2);
    float4 o;
    const float a0 = acc[bi][0] + bias[(tx << 2) + 0];
    const float a1 = acc[bi][1] + bias[(tx << 2) + 1];
    const float a2 = acc[bi][2] + bias[(tx << 2) + 2];
    const float a3 = acc[bi][3] + bias[(tx << 2) + 3];
    if (MODE == 0) {
      o.x = sigmoidf_(a0); o.y = sigmoidf_(a1); o.z = sigmoidf_(a2); o.w = sigmoidf_(a3);
    } else if (MODE == 1) {
      const float4 st = *(const float4*)&state[base];
      o.x = sigmoidf_(a0) * st.x; o.y = sigmoidf_(a1) * st.y;
      o.z = sigmoidf_(a2) * st.z; o.w = sigmoidf_(a3) * st.w;
    } else {
      const float4 st = *(const float4*)&state[base];
      const float4 zv = *(const float4*)&zb[base];
      o.x = zv.x * st.x + (1.f - zv.x) * tanhf(a0);
      o.y = zv.y * st.y + (1.f - zv.y) * tanhf(a1);
      o.z = zv.z * st.z + (1.f - zv.z) * tanhf(a2);
      o.w = zv.w * st.w + (1.f - zv.w) * tanhf(a3);
    }
    *(float4*)&dst[base] = o;
  }
}

extern "C" void kernel_launch(void* const* d_in, const int* in_sizes, int n_in,
                              void* d_out, int out_size, void* d_ws, size_t ws_size,
                              hipStream_t stream) {
  const float* x     = (const float*)d_in[0];
  const float* state = (const float*)d_in[1];
  const float* emb   = (const float*)d_in[2];
  const float* Wg    = (const float*)d_in[3];
  const float* bg    = (const float*)d_in[4];
  const float* Wu    = (const float*)d_in[5];
  const float* bu    = (const float*)d_in[6];
  float* out = (float*)d_out;

  char* w = (char*)d_ws;
  float*    Y1f  = (float*)(w);                                // 32 MB  [n][8192]
  float*    Y2f  = (float*)(w + ((size_t)32 << 20));           // 32 MB
  ushort_t* T0th = (ushort_t*)(w + ((size_t)64 << 20));        // 16 MB  [j][1024]
  ushort_t* T0tl = (ushort_t*)(w + ((size_t)80 << 20));        // 16 MB
  ushort_t* Y1th = (ushort_t*)(w + ((size_t)96 << 20));        // 16 MB
  ushort_t* Y1tl = (ushort_t*)(w + ((size_t)112 << 20));       // 16 MB
  float*    rs   = (float*)(w + ((size_t)128 << 20));          // 16 MB  [b][n][64]
  ushort_t* Ah   = (ushort_t*)(w + ((size_t)144 << 20));       // 2 MB
  ushort_t* Al   = (ushort_t*)(w + ((size_t)146 << 20));       // 2 MB
  ushort_t* Wn   = (ushort_t*)(w + ((size_t)148 << 20));       // 48 MB -> end 196 MB
  float* zb = out;

  const dim3 gg(64, 8);       // GEMM grid (j-tiles, n-tiles)
  const dim3 gt(8, 64);       // build_T0t (n-tiles, b)
  const dim3 gw(24, 128);     // wcombine halves

  compute_A_kernel<<<N_, 256, 0, stream>>>(emb, Ah, Al);

  // ---- gate pass ----
  build_T0t_kernel<<<gt, 256, 0, stream>>>(x, state, T0th, T0tl);
  mfma_gemm_kernel<1><<<gg, 256, 0, stream>>>(Ah, Al, T0th, T0tl, nullptr, nullptr, Y1f, Y1th, Y1tl);
  mfma_gemm_kernel<0><<<gg, 256, 0, stream>>>(Ah, Al, Y1th, Y1tl, T0th, T0tl, Y2f, nullptr, nullptr);
  wcombine_half_kernel<128><<<gw, 256, 0, stream>>>(emb, Wg, 0, Wn);
  pernode64_kernel<0><<<N_, 256, 0, stream>>>(x, state, Y1f, Y2f, Wn, emb, bg, 128,
                                              nullptr, nullptr, zb);
  wcombine_half_kernel<128><<<gw, 256, 0, stream>>>(emb, Wg, 64, Wn);
  pernode64_kernel<1><<<N_, 256, 0, stream>>>(x, state, Y1f, Y2f, Wn, emb, bg + 64, 128,
                                              state, nullptr, rs);

  // ---- update pass ----
  build_T0t_kernel<<<gt, 256, 0, stream>>>(x, rs, T0th, T0tl);
  mfma_gemm_kernel<1><<<gg, 256, 0, stream>>>(Ah, Al, T0th, T0tl, nullptr, nullptr, Y1f, Y1th, Y1tl);
  mfma_gemm_kernel<0><<<gg, 256, 0, stream>>>(Ah, Al, Y1th, Y1tl, T0th, T0tl, Y2f, nullptr, nullptr);
  wcombine_half_kernel<64><<<gw, 256, 0, stream>>>(emb, Wu, 0, Wn);
  pernode64_kernel<2><<<N_, 256, 0, stream>>>(x, rs, Y1f, Y2f, Wn, emb, bu, 64,
                                              state, zb, out);
}